// Round 21
// baseline (160.562 us; speedup 1.0000x reference)
//
#include <hip/hip_runtime.h>
#include <hip/hip_bf16.h>
#include <stdint.h>

// Problem: B=4, S=2048, D=1024, H=16, hd=64.
// fp32 inputs (x, wq, wk, wv), fp32 OUTPUT [B,S,D].
// Pipeline: cvt_all -> qkv_gemm (bf16 MFMA) -> flash attn.
// R20->R21 (GEMM-only): BK 32 -> 64. Halves barrier count (the ~20% vmcnt
// drain per m97 analysis). Staging/read index scheme is a TRANSPLANT of
// attn's 9-round-proven pattern ([rows][64-elem] tiles, 8-chunk XOR
// involution ssc=(sbc^(srow&7))*8, frag reads (kk*4+G)^sw) — zero measured
// bank conflicts in attn. Per-kk frag loads keep VGPR flat. LDS 16->32KB.
// Attn/cvt byte-identical to R20 (156.7us: 84.9us attn w/ base-pointer
// ds_reads + setprio; R17 GEMM swizzles elsewhere unchanged).
// Buffer plan:
//   d_out[0,16M)  xbf  bf16 [8192][1024]  (scratch; dead before attn O-writes)
//   ws[0,6M)      wT   bf16 [3072][1024]
//   ws[6M,22M)    qb   bf16 [64 pair][2048][64]  (pre-scaled by 0.125*log2e)
//   ws[22M,38M)   kb   bf16 [64 pair][2048][64]
//   ws[38M,54M)   vtb  bf16 [64 pair][64][2048]  (V transposed)

typedef __hip_bfloat16 bf16;
typedef __attribute__((ext_vector_type(8))) short short8;
typedef __attribute__((ext_vector_type(4))) float f32x4;
typedef __attribute__((ext_vector_type(4))) unsigned int u32x4;
typedef __attribute__((ext_vector_type(8))) unsigned short ushort8;
typedef __attribute__((ext_vector_type(4))) unsigned short ushort4v;

#define MFMA_16x16x32(a, b, c) __builtin_amdgcn_mfma_f32_16x16x32_bf16((a), (b), (c), 0, 0, 0)

__device__ __forceinline__ void gload_lds16(const void* g, void* l) {
  __builtin_amdgcn_global_load_lds((const __attribute__((address_space(1))) unsigned int*)g,
                                   (__attribute__((address_space(3))) unsigned int*)l,
                                   16, 0, 0);
}

__device__ __forceinline__ unsigned short bfu(float f) {
  return __bfloat16_as_ushort(__float2bfloat16(f));
}
__device__ __forceinline__ unsigned int pack2(float lo, float hi) {
  unsigned int r;
  asm("v_cvt_pk_bf16_f32 %0, %1, %2" : "=v"(r) : "v"(lo), "v"(hi));
  return r;
}
__device__ __forceinline__ float exp2_fast(float x) {   // D = 2^S0 (ISA v_exp_f32)
  float r;
  asm("v_exp_f32 %0, %1" : "=v"(r) : "v"(x));
  return r;
}

// ---------- fused convert: x fp32->bf16  |  w fp32->bf16 transposed ----------
__global__ __launch_bounds__(256) void cvt_all_kernel(const float* __restrict__ x,
                                                      const float* __restrict__ w0,
                                                      const float* __restrict__ w1,
                                                      const float* __restrict__ w2,
                                                      bf16* __restrict__ xbf,
                                                      bf16* __restrict__ wT) {
  __shared__ float tile[64][65];
  const int t = threadIdx.x;
  const int bid = blockIdx.x;
  if (bid < 4096) {                      // ---- x convert: 8 elems/thread
    int i = bid * 256 + t;
    const float4* xv = (const float4*)x;
    float4 a = xv[i * 2];
    float4 b = xv[i * 2 + 1];
    ushort8 o;
    o[0] = bfu(a.x); o[1] = bfu(a.y); o[2] = bfu(a.z); o[3] = bfu(a.w);
    o[4] = bfu(b.x); o[5] = bfu(b.y); o[6] = bfu(b.z); o[7] = bfu(b.w);
    ((ushort8*)xbf)[i] = o;
    return;
  }
  // ---- w transpose+convert: w[k][n] -> wT[n][k]
  const int wb = bid - 4096;
  const int mat = wb >> 8;
  const int rem = wb & 255;
  const int k0 = (rem >> 4) * 64;
  const int n0 = (rem & 15) * 64;
  const float* w = (mat == 0) ? w0 : ((mat == 1) ? w1 : w2);
#pragma unroll
  for (int it = 0; it < 4; ++it) {
    int lin = it * 1024 + t * 4;
    int row = lin >> 6, col = lin & 63;
    float4 v = *(const float4*)&w[(size_t)(k0 + row) * 1024 + n0 + col];
    tile[row][col] = v.x; tile[row][col + 1] = v.y;
    tile[row][col + 2] = v.z; tile[row][col + 3] = v.w;
  }
  __syncthreads();
#pragma unroll
  for (int it = 0; it < 2; ++it) {
    int chunk = it * 256 + t;
    int nrow = chunk >> 3, kc = chunk & 7;
    ushort8 o;
#pragma unroll
    for (int j = 0; j < 8; ++j) o[j] = bfu(tile[kc * 8 + j][nrow]);
    *(ushort8*)&wT[((size_t)mat * 1024 + n0 + nrow) * 1024 + k0 + kc * 8] = o;
  }
}

// ---------------- QKV GEMM: [8192,1024] x [1024,3072] -------------------
// 128x128 tile, BK=64 (16 K-iters, barriers halved), 4 waves (2x2), per-kk
// 4x4 16x16x32 MFMA. Staging/read pattern transplanted from attn (proven
// zero-conflict): [row][64-elem] tiles, 8-chunk XOR involution, frag reads
// at (kk*4+G)^sw. T1 XCD grid swizzle, vtb 8B stores.
__global__ __launch_bounds__(256) void qkv_gemm_kernel(const bf16* __restrict__ A,
                                                       const bf16* __restrict__ Wt,
                                                       bf16* __restrict__ qb,
                                                       bf16* __restrict__ kb,
                                                       bf16* __restrict__ vtb) {
  __shared__ bf16 As[128 * 64];
  __shared__ bf16 Bs[128 * 64];
  const int t = threadIdx.x;
  const int w = t >> 6;
  const int lane = t & 63;
  const int G = lane >> 4, lq = lane & 15;
  const int sw = lq & 7;                       // frag-read XOR (row&7 = lq&7)
  const int bid = blockIdx.x;                  // 1536 blocks
  const int xcd = bid & 7, p = bid >> 3;       // p in [0,192)
  const int m0 = (xcd * 8 + (p & 7)) * 128;
  const int n0 = (p >> 3) * 128;
  const int wr = w >> 1, wc = w & 1;

  const f32x4 fzero = {0.f, 0.f, 0.f, 0.f};
  f32x4 acc[4][4];
#pragma unroll
  for (int i = 0; i < 4; ++i)
#pragma unroll
    for (int j = 0; j < 4; ++j) acc[i][j] = fzero;

  // staging (attn pattern): srow = t>>3 in [0,32); 4 g-groups cover 128 rows.
  // LDS dest linear (g*2048 + w*512 elems); source chunk = (t&7) ^ (srow&7).
  const int srow = t >> 3, sbc = t & 7;
  const int ssc = (sbc ^ (srow & 7)) * 8;

  for (int k0 = 0; k0 < 1024; k0 += 64) {
#pragma unroll
    for (int g = 0; g < 4; ++g) {
      gload_lds16(&A[(size_t)(m0 + g * 32 + srow) * 1024 + k0 + ssc],
                  &As[(size_t)(g * 2048 + w * 512)]);
      gload_lds16(&Wt[(size_t)(n0 + g * 32 + srow) * 1024 + k0 + ssc],
                  &Bs[(size_t)(g * 2048 + w * 512)]);
    }
    __syncthreads();
#pragma unroll
    for (int kk = 0; kk < 2; ++kk) {
      short8 af[4], bfr[4];
#pragma unroll
      for (int i = 0; i < 4; ++i)
        af[i] = *(const short8*)&As[(wr * 64 + i * 16 + lq) * 64 + ((kk * 4 + G) ^ sw) * 8];
#pragma unroll
      for (int j = 0; j < 4; ++j)
        bfr[j] = *(const short8*)&Bs[(wc * 64 + j * 16 + lq) * 64 + ((kk * 4 + G) ^ sw) * 8];
#pragma unroll
      for (int i = 0; i < 4; ++i)
#pragma unroll
        for (int j = 0; j < 4; ++j)
          acc[i][j] = MFMA_16x16x32(af[i], bfr[j], acc[i][j]);
    }
    __syncthreads();
  }

  const int matid = n0 >> 10;
  const int nb = n0 & 1023;
  if (matid == 2) {
    // V^T: thread's 4 r-values are 4 consecutive s at fixed d -> 8B store
#pragma unroll
    for (int i = 0; i < 4; ++i) {
      int mm = m0 + wr * 64 + i * 16 + G * 4;  // r=0 base; 4 consecutive
      int b = mm >> 11, s = mm & 2047;
#pragma unroll
      for (int j = 0; j < 4; ++j) {
        int nn = nb + wc * 64 + j * 16 + lq;
        int h = nn >> 6, d = nn & 63;
        ushort4v o;
#pragma unroll
        for (int r = 0; r < 4; ++r) o[r] = bfu(acc[i][j][r]);
        *(ushort4v*)&vtb[((size_t)(b * 16 + h) * 64 + d) * 2048 + s] = o;
      }
    }
  } else {
    const float scale = (matid == 0) ? 0.18033688011112f : 1.0f;  // 1/8*log2e | 1
    bf16* dst = (matid == 0) ? qb : kb;
#pragma unroll
    for (int i = 0; i < 4; ++i) {
#pragma unroll
      for (int r = 0; r < 4; ++r) {
        int mm = m0 + wr * 64 + i * 16 + G * 4 + r;
        int b = mm >> 11, s = mm & 2047;
#pragma unroll
        for (int j = 0; j < 4; ++j) {
          int nn = nb + wc * 64 + j * 16 + lq;
          int h = nn >> 6, d = nn & 63;
          dst[((size_t)(b * 16 + h) * 2048 + s) * 64 + d] =
              __float2bfloat16(acc[i][j][r] * scale);
        }
      }
    }
  }
}

// ---------------- flash attention (MFMA, LDS-staged K/V, swapped QK^T) -----
// R20 kernel (proven 84.9us): KVBLK=64 double-buffered staging, K bit-perm
// (QK^T C-layout == PV B-frag lane-locally), XOR swizzle, exp2 softmax,
// ones-MFMA row sums, T5 setprio, precomputed base-pointer ds_reads.
__global__ __launch_bounds__(256) void attn_kernel(const bf16* __restrict__ Q,
                                                   const bf16* __restrict__ K,
                                                   const bf16* __restrict__ VT,
                                                   float* __restrict__ O) {
  __shared__ bf16 Kb[2][4096];                 // [buf][64 kv(perm)][64 d] swizzled
  __shared__ bf16 Vb[2][4096];                 // [buf][64 d][64 kv] swizzled
  const int t = threadIdx.x;
  const int w = t >> 6, lane = t & 63;
  const int G = lane >> 4, lq = lane & 15;
  const int sw = lq & 7;                       // frag-read swizzle
  const int bid = blockIdx.x;
  const int pair = (((bid >> 7) & 7) << 3) | (bid & 7);  // 16 chunks of a pair on one XCD
  const int chunk = (bid >> 3) & 15;
  const int b = pair >> 4, h = pair & 15;
  const size_t base = (size_t)pair * (2048 * 64);
  const int q0 = chunk * 128 + w * 32;         // 32 q-rows per wave

  const f32x4 fzero = {0.f, 0.f, 0.f, 0.f};
  short8 ones;                                 // bf16 1.0 x8 (A-frag for row sums)
#pragma unroll
  for (int j = 0; j < 8; ++j) ones[j] = (short)0x3F80;

  const int srow = t >> 3, sbc = t & 7;
  const int ssc = (sbc ^ (srow & 7)) * 8;      // swizzled chunk (involution, per dest row)
  const int kprow = ((srow & 12) << 1) | ((srow & 16) >> 2) | (srow & 3);  // perm32(srow)

  // lane-constant XOR variants shared by K(hf) and V(h2):
  const int e0 = (G ^ sw) * 8;                 // hf=0 / h2=0
  const int e1 = ((4 + G) ^ sw) * 8;           // hf=1 / h2=1
  // 8 precomputed LDS base pointers; all reads = base + compile-time offset
  const bf16* kB0[2] = { &Kb[0][lq * 64 + e0], &Kb[1][lq * 64 + e0] };
  const bf16* kB1[2] = { &Kb[0][lq * 64 + e1], &Kb[1][lq * 64 + e1] };
  const bf16* vB0[2] = { &Vb[0][lq * 64 + e0], &Vb[1][lq * 64 + e0] };
  const bf16* vB1[2] = { &Vb[0][lq * 64 + e1], &Vb[1][lq * 64 + e1] };

#define STAGE_TILE(kvbase, bufi)                                                   \
  do {                                                                             \
    gload_lds16(&K[base + (size_t)((kvbase) + kprow) * 64 + ssc],                  \
                &Kb[bufi][(size_t)(w * 64) * 8]);                                  \
    gload_lds16(&K[base + (size_t)((kvbase) + 32 + kprow) * 64 + ssc],             \
                &Kb[bufi][(size_t)(256 + w * 64) * 8]);                            \
    gload_lds16(&VT[base + (size_t)srow * 2048 + (kvbase) + ssc],                  \
                &Vb[bufi][(size_t)(w * 64) * 8]);                                  \
    gload_lds16(&VT[base + (size_t)(32 + srow) * 2048 + (kvbase) + ssc],           \
                &Vb[bufi][(size_t)(256 + w * 64) * 8]);                            \
  } while (0)

#define TILE_COMPUTE(BUF)                                                          \
  _Pragma("unroll")                                                                \
  for (int h2 = 0; h2 < 2; ++h2) {                                                 \
    short8 kf0[2], kf1[2], vf[4];                                                  \
    kf0[0] = *(const short8*)(kB0[BUF] + (h2 * 2 + 0) * 1024);                     \
    kf0[1] = *(const short8*)(kB1[BUF] + (h2 * 2 + 0) * 1024);                     \
    kf1[0] = *(const short8*)(kB0[BUF] + (h2 * 2 + 1) * 1024);                     \
    kf1[1] = *(const short8*)(kB1[BUF] + (h2 * 2 + 1) * 1024);                     \
    _Pragma("unroll")                                                              \
    for (int dt = 0; dt < 4; ++dt)                                                 \
      vf[dt] = h2 ? *(const short8*)(vB1[BUF] + dt * 1024)                         \
                  : *(const short8*)(vB0[BUF] + dt * 1024);                        \
    __builtin_amdgcn_s_setprio(1);                                                 \
    _Pragma("unroll")                                                              \
    for (int qt = 0; qt < 2; ++qt) {                                               \
      f32x4 s0 = MFMA_16x16x32(kf0[0], qf[qt][0], fzero);                          \
      s0 = MFMA_16x16x32(kf0[1], qf[qt][1], s0);                                   \
      f32x4 s1 = MFMA_16x16x32(kf1[0], qf[qt][0], fzero);                          \
      s1 = MFMA_16x16x32(kf1[1], qf[qt][1], s1);                                   \
      u32x4 pw;                                                                    \
      pw[0] = pack2(exp2_fast(s0[0]), exp2_fast(s0[1]));                           \
      pw[1] = pack2(exp2_fast(s0[2]), exp2_fast(s0[3]));                           \
      pw[2] = pack2(exp2_fast(s1[0]), exp2_fast(s1[1]));                           \
      pw[3] = pack2(exp2_fast(s1[2]), exp2_fast(s1[3]));                           \
      short8 pf = __builtin_bit_cast(short8, pw);                                  \
      lacc[qt] = MFMA_16x16x32(ones, pf, lacc[qt]);                                \
      _Pragma("unroll")                                                            \
      for (int dt = 0; dt < 4; ++dt)                                               \
        acc[qt][dt] = MFMA_16x16x32(vf[dt], pf, acc[qt][dt]);                      \
    }                                                                              \
    __builtin_amdgcn_s_setprio(0);                                                 \
  }

  short8 qf[2][2];
#pragma unroll
  for (int qt = 0; qt < 2; ++qt)
#pragma unroll
    for (int hf = 0; hf < 2; ++hf)
      qf[qt][hf] = *(const short8*)&Q[base + (size_t)(q0 + qt * 16 + lq) * 64 + hf * 32 + G * 8];

  f32x4 acc[2][4];
#pragma unroll
  for (int qt = 0; qt < 2; ++qt)
#pragma unroll
    for (int dt = 0; dt < 4; ++dt) acc[qt][dt] = fzero;
  f32x4 lacc[2] = {fzero, fzero};              // row-sum accumulators (MFMA)

  STAGE_TILE(0, 0);
  __syncthreads();

  for (int it2 = 0; it2 < 16; ++it2) {
    const int kvc = it2 * 128;
    STAGE_TILE(kvc + 64, 1);
    TILE_COMPUTE(0)
    __syncthreads();                           // buf1 staged; buf0 reads done
    if (it2 != 15) {
      STAGE_TILE(kvc + 128, 0);
    }
    TILE_COMPUTE(1)
    __syncthreads();                           // buf0 staged; buf1 reads done
  }

  // O^T[d][q] -> out[b][s][h*64+d] (fp32); lane q = lq, d = dt*16 + 4G + r
#pragma unroll
  for (int qt = 0; qt < 2; ++qt) {
    float inv = 1.f / lacc[qt][0];             // full row sum (MFMA-reduced, all lanes)
    size_t rowoff = ((size_t)b * 2048 + q0 + qt * 16 + lq) * 1024 + h * 64;
#pragma unroll
    for (int dt = 0; dt < 4; ++dt) {
      f32x4 o;
#pragma unroll
      for (int r = 0; r < 4; ++r) o[r] = acc[qt][dt][r] * inv;
      *(f32x4*)&O[rowoff + dt * 16 + G * 4] = o;
    }
  }
#undef STAGE_TILE
#undef TILE_COMPUTE
}

extern "C" void kernel_launch(void* const* d_in, const int* in_sizes, int n_in,
                              void* d_out, int out_size, void* d_ws, size_t ws_size,
                              hipStream_t stream) {
  const float* x = (const float*)d_in[0];
  const float* wq = (const float*)d_in[1];
  const float* wk = (const float*)d_in[2];
  const float* wv = (const float*)d_in[3];
  float* out = (float*)d_out;            // fp32 output
  char* ws = (char*)d_ws;

  const size_t MB = 1024 * 1024;
  bf16* xbf = (bf16*)d_out;              // 16 MB scratch; dead before attn writes O
  bf16* wT = (bf16*)(ws);                // 6 MB
  bf16* qb = (bf16*)(ws + 6 * MB);       // 16 MB
  bf16* kb = (bf16*)(ws + 22 * MB);      // 16 MB
  bf16* vtb = (bf16*)(ws + 38 * MB);     // 16 MB

  hipLaunchKernelGGL(cvt_all_kernel, dim3(4864), dim3(256), 0, stream,
                     x, wq, wk, wv, xbf, wT);
  hipLaunchKernelGGL(qkv_gemm_kernel, dim3(1536), dim3(256), 0, stream, xbf, wT, qb, kb, vtb);
  hipLaunchKernelGGL(attn_kernel, dim3(1024), dim3(256), 0, stream, qb, kb, vtb, out);
}

// Round 22
// 160.118 us; speedup vs baseline: 1.0028x; 1.0028x over previous
//
#include <hip/hip_runtime.h>
#include <hip/hip_bf16.h>
#include <stdint.h>

// Problem: B=4, S=2048, D=1024, H=16, hd=64.
// fp32 inputs (x, wq, wk, wv), fp32 OUTPUT [B,S,D].
// Pipeline: cvt_all -> qkv_gemm (bf16 MFMA) -> flash attn.
// R20->R21 (GEMM-only): BK 32 -> 64. Halves barrier count (the ~20% vmcnt
// drain per m97 analysis). Staging/read index scheme is a TRANSPLANT of
// attn's 9-round-proven pattern ([rows][64-elem] tiles, 8-chunk XOR
// involution ssc=(sbc^(srow&7))*8, frag reads (kk*4+G)^sw) — zero measured
// bank conflicts in attn. Per-kk frag loads keep VGPR flat. LDS 16->32KB.
// Attn/cvt byte-identical to R20 (156.7us: 84.9us attn w/ base-pointer
// ds_reads + setprio; R17 GEMM swizzles elsewhere unchanged).
// Buffer plan:
//   d_out[0,16M)  xbf  bf16 [8192][1024]  (scratch; dead before attn O-writes)
//   ws[0,6M)      wT   bf16 [3072][1024]
//   ws[6M,22M)    qb   bf16 [64 pair][2048][64]  (pre-scaled by 0.125*log2e)
//   ws[22M,38M)   kb   bf16 [64 pair][2048][64]
//   ws[38M,54M)   vtb  bf16 [64 pair][64][2048]  (V transposed)

typedef __hip_bfloat16 bf16;
typedef __attribute__((ext_vector_type(8))) short short8;
typedef __attribute__((ext_vector_type(4))) float f32x4;
typedef __attribute__((ext_vector_type(4))) unsigned int u32x4;
typedef __attribute__((ext_vector_type(8))) unsigned short ushort8;
typedef __attribute__((ext_vector_type(4))) unsigned short ushort4v;

#define MFMA_16x16x32(a, b, c) __builtin_amdgcn_mfma_f32_16x16x32_bf16((a), (b), (c), 0, 0, 0)

__device__ __forceinline__ void gload_lds16(const void* g, void* l) {
  __builtin_amdgcn_global_load_lds((const __attribute__((address_space(1))) unsigned int*)g,
                                   (__attribute__((address_space(3))) unsigned int*)l,
                                   16, 0, 0);
}

__device__ __forceinline__ unsigned short bfu(float f) {
  return __bfloat16_as_ushort(__float2bfloat16(f));
}
__device__ __forceinline__ unsigned int pack2(float lo, float hi) {
  unsigned int r;
  asm("v_cvt_pk_bf16_f32 %0, %1, %2" : "=v"(r) : "v"(lo), "v"(hi));
  return r;
}
__device__ __forceinline__ float exp2_fast(float x) {   // D = 2^S0 (ISA v_exp_f32)
  float r;
  asm("v_exp_f32 %0, %1" : "=v"(r) : "v"(x));
  return r;
}

// ---------- fused convert: x fp32->bf16  |  w fp32->bf16 transposed ----------
__global__ __launch_bounds__(256) void cvt_all_kernel(const float* __restrict__ x,
                                                      const float* __restrict__ w0,
                                                      const float* __restrict__ w1,
                                                      const float* __restrict__ w2,
                                                      bf16* __restrict__ xbf,
                                                      bf16* __restrict__ wT) {
  __shared__ float tile[64][65];
  const int t = threadIdx.x;
  const int bid = blockIdx.x;
  if (bid < 4096) {                      // ---- x convert: 8 elems/thread
    int i = bid * 256 + t;
    const float4* xv = (const float4*)x;
    float4 a = xv[i * 2];
    float4 b = xv[i * 2 + 1];
    ushort8 o;
    o[0] = bfu(a.x); o[1] = bfu(a.y); o[2] = bfu(a.z); o[3] = bfu(a.w);
    o[4] = bfu(b.x); o[5] = bfu(b.y); o[6] = bfu(b.z); o[7] = bfu(b.w);
    ((ushort8*)xbf)[i] = o;
    return;
  }
  // ---- w transpose+convert: w[k][n] -> wT[n][k]
  const int wb = bid - 4096;
  const int mat = wb >> 8;
  const int rem = wb & 255;
  const int k0 = (rem >> 4) * 64;
  const int n0 = (rem & 15) * 64;
  const float* w = (mat == 0) ? w0 : ((mat == 1) ? w1 : w2);
#pragma unroll
  for (int it = 0; it < 4; ++it) {
    int lin = it * 1024 + t * 4;
    int row = lin >> 6, col = lin & 63;
    float4 v = *(const float4*)&w[(size_t)(k0 + row) * 1024 + n0 + col];
    tile[row][col] = v.x; tile[row][col + 1] = v.y;
    tile[row][col + 2] = v.z; tile[row][col + 3] = v.w;
  }
  __syncthreads();
#pragma unroll
  for (int it = 0; it < 2; ++it) {
    int chunk = it * 256 + t;
    int nrow = chunk >> 3, kc = chunk & 7;
    ushort8 o;
#pragma unroll
    for (int j = 0; j < 8; ++j) o[j] = bfu(tile[kc * 8 + j][nrow]);
    *(ushort8*)&wT[((size_t)mat * 1024 + n0 + nrow) * 1024 + k0 + kc * 8] = o;
  }
}

// ---------------- QKV GEMM: [8192,1024] x [1024,3072] -------------------
// 128x128 tile, BK=64 (16 K-iters, barriers halved), 4 waves (2x2), per-kk
// 4x4 16x16x32 MFMA. Staging/read pattern transplanted from attn (proven
// zero-conflict): [row][64-elem] tiles, 8-chunk XOR involution, frag reads
// at (kk*4+G)^sw. T1 XCD grid swizzle, vtb 8B stores.
__global__ __launch_bounds__(256) void qkv_gemm_kernel(const bf16* __restrict__ A,
                                                       const bf16* __restrict__ Wt,
                                                       bf16* __restrict__ qb,
                                                       bf16* __restrict__ kb,
                                                       bf16* __restrict__ vtb) {
  __shared__ bf16 As[128 * 64];
  __shared__ bf16 Bs[128 * 64];
  const int t = threadIdx.x;
  const int w = t >> 6;
  const int lane = t & 63;
  const int G = lane >> 4, lq = lane & 15;
  const int sw = lq & 7;                       // frag-read XOR (row&7 = lq&7)
  const int bid = blockIdx.x;                  // 1536 blocks
  const int xcd = bid & 7, p = bid >> 3;       // p in [0,192)
  const int m0 = (xcd * 8 + (p & 7)) * 128;
  const int n0 = (p >> 3) * 128;
  const int wr = w >> 1, wc = w & 1;

  const f32x4 fzero = {0.f, 0.f, 0.f, 0.f};
  f32x4 acc[4][4];
#pragma unroll
  for (int i = 0; i < 4; ++i)
#pragma unroll
    for (int j = 0; j < 4; ++j) acc[i][j] = fzero;

  // staging (attn pattern): srow = t>>3 in [0,32); 4 g-groups cover 128 rows.
  // LDS dest linear (g*2048 + w*512 elems); source chunk = (t&7) ^ (srow&7).
  const int srow = t >> 3, sbc = t & 7;
  const int ssc = (sbc ^ (srow & 7)) * 8;

  for (int k0 = 0; k0 < 1024; k0 += 64) {
#pragma unroll
    for (int g = 0; g < 4; ++g) {
      gload_lds16(&A[(size_t)(m0 + g * 32 + srow) * 1024 + k0 + ssc],
                  &As[(size_t)(g * 2048 + w * 512)]);
      gload_lds16(&Wt[(size_t)(n0 + g * 32 + srow) * 1024 + k0 + ssc],
                  &Bs[(size_t)(g * 2048 + w * 512)]);
    }
    __syncthreads();
#pragma unroll
    for (int kk = 0; kk < 2; ++kk) {
      short8 af[4], bfr[4];
#pragma unroll
      for (int i = 0; i < 4; ++i)
        af[i] = *(const short8*)&As[(wr * 64 + i * 16 + lq) * 64 + ((kk * 4 + G) ^ sw) * 8];
#pragma unroll
      for (int j = 0; j < 4; ++j)
        bfr[j] = *(const short8*)&Bs[(wc * 64 + j * 16 + lq) * 64 + ((kk * 4 + G) ^ sw) * 8];
#pragma unroll
      for (int i = 0; i < 4; ++i)
#pragma unroll
        for (int j = 0; j < 4; ++j)
          acc[i][j] = MFMA_16x16x32(af[i], bfr[j], acc[i][j]);
    }
    __syncthreads();
  }

  const int matid = n0 >> 10;
  const int nb = n0 & 1023;
  if (matid == 2) {
    // V^T: thread's 4 r-values are 4 consecutive s at fixed d -> 8B store
#pragma unroll
    for (int i = 0; i < 4; ++i) {
      int mm = m0 + wr * 64 + i * 16 + G * 4;  // r=0 base; 4 consecutive
      int b = mm >> 11, s = mm & 2047;
#pragma unroll
      for (int j = 0; j < 4; ++j) {
        int nn = nb + wc * 64 + j * 16 + lq;
        int h = nn >> 6, d = nn & 63;
        ushort4v o;
#pragma unroll
        for (int r = 0; r < 4; ++r) o[r] = bfu(acc[i][j][r]);
        *(ushort4v*)&vtb[((size_t)(b * 16 + h) * 64 + d) * 2048 + s] = o;
      }
    }
  } else {
    const float scale = (matid == 0) ? 0.18033688011112f : 1.0f;  // 1/8*log2e | 1
    bf16* dst = (matid == 0) ? qb : kb;
#pragma unroll
    for (int i = 0; i < 4; ++i) {
#pragma unroll
      for (int r = 0; r < 4; ++r) {
        int mm = m0 + wr * 64 + i * 16 + G * 4 + r;
        int b = mm >> 11, s = mm & 2047;
#pragma unroll
        for (int j = 0; j < 4; ++j) {
          int nn = nb + wc * 64 + j * 16 + lq;
          int h = nn >> 6, d = nn & 63;
          dst[((size_t)(b * 16 + h) * 2048 + s) * 64 + d] =
              __float2bfloat16(acc[i][j][r] * scale);
        }
      }
    }
  }
}

// ---------------- flash attention (MFMA, LDS-staged K/V, swapped QK^T) -----
// R20 kernel (proven 84.9us): KVBLK=64 double-buffered staging, K bit-perm
// (QK^T C-layout == PV B-frag lane-locally), XOR swizzle, exp2 softmax,
// ones-MFMA row sums, T5 setprio, precomputed base-pointer ds_reads.
__global__ __launch_bounds__(256) void attn_kernel(const bf16* __restrict__ Q,
                                                   const bf16* __restrict__ K,
                                                   const bf16* __restrict__ VT,
                                                   float* __restrict__ O) {
  __shared__ bf16 Kb[2][4096];                 // [buf][64 kv(perm)][64 d] swizzled
  __shared__ bf16 Vb[2][4096];                 // [buf][64 d][64 kv] swizzled
  const int t = threadIdx.x;
  const int w = t >> 6, lane = t & 63;
  const int G = lane >> 4, lq = lane & 15;
  const int sw = lq & 7;                       // frag-read swizzle
  const int bid = blockIdx.x;
  const int pair = (((bid >> 7) & 7) << 3) | (bid & 7);  // 16 chunks of a pair on one XCD
  const int chunk = (bid >> 3) & 15;
  const int b = pair >> 4, h = pair & 15;
  const size_t base = (size_t)pair * (2048 * 64);
  const int q0 = chunk * 128 + w * 32;         // 32 q-rows per wave

  const f32x4 fzero = {0.f, 0.f, 0.f, 0.f};
  short8 ones;                                 // bf16 1.0 x8 (A-frag for row sums)
#pragma unroll
  for (int j = 0; j < 8; ++j) ones[j] = (short)0x3F80;

  const int srow = t >> 3, sbc = t & 7;
  const int ssc = (sbc ^ (srow & 7)) * 8;      // swizzled chunk (involution, per dest row)
  const int kprow = ((srow & 12) << 1) | ((srow & 16) >> 2) | (srow & 3);  // perm32(srow)

  // lane-constant XOR variants shared by K(hf) and V(h2):
  const int e0 = (G ^ sw) * 8;                 // hf=0 / h2=0
  const int e1 = ((4 + G) ^ sw) * 8;           // hf=1 / h2=1
  // 8 precomputed LDS base pointers; all reads = base + compile-time offset
  const bf16* kB0[2] = { &Kb[0][lq * 64 + e0], &Kb[1][lq * 64 + e0] };
  const bf16* kB1[2] = { &Kb[0][lq * 64 + e1], &Kb[1][lq * 64 + e1] };
  const bf16* vB0[2] = { &Vb[0][lq * 64 + e0], &Vb[1][lq * 64 + e0] };
  const bf16* vB1[2] = { &Vb[0][lq * 64 + e1], &Vb[1][lq * 64 + e1] };

#define STAGE_TILE(kvbase, bufi)                                                   \
  do {                                                                             \
    gload_lds16(&K[base + (size_t)((kvbase) + kprow) * 64 + ssc],                  \
                &Kb[bufi][(size_t)(w * 64) * 8]);                                  \
    gload_lds16(&K[base + (size_t)((kvbase) + 32 + kprow) * 64 + ssc],             \
                &Kb[bufi][(size_t)(256 + w * 64) * 8]);                            \
    gload_lds16(&VT[base + (size_t)srow * 2048 + (kvbase) + ssc],                  \
                &Vb[bufi][(size_t)(w * 64) * 8]);                                  \
    gload_lds16(&VT[base + (size_t)(32 + srow) * 2048 + (kvbase) + ssc],           \
                &Vb[bufi][(size_t)(256 + w * 64) * 8]);                            \
  } while (0)

#define TILE_COMPUTE(BUF)                                                          \
  _Pragma("unroll")                                                                \
  for (int h2 = 0; h2 < 2; ++h2) {                                                 \
    short8 kf0[2], kf1[2], vf[4];                                                  \
    kf0[0] = *(const short8*)(kB0[BUF] + (h2 * 2 + 0) * 1024);                     \
    kf0[1] = *(const short8*)(kB1[BUF] + (h2 * 2 + 0) * 1024);                     \
    kf1[0] = *(const short8*)(kB0[BUF] + (h2 * 2 + 1) * 1024);                     \
    kf1[1] = *(const short8*)(kB1[BUF] + (h2 * 2 + 1) * 1024);                     \
    _Pragma("unroll")                                                              \
    for (int dt = 0; dt < 4; ++dt)                                                 \
      vf[dt] = h2 ? *(const short8*)(vB1[BUF] + dt * 1024)                         \
                  : *(const short8*)(vB0[BUF] + dt * 1024);                        \
    __builtin_amdgcn_s_setprio(1);                                                 \
    _Pragma("unroll")                                                              \
    for (int qt = 0; qt < 2; ++qt) {                                               \
      f32x4 s0 = MFMA_16x16x32(kf0[0], qf[qt][0], fzero);                          \
      s0 = MFMA_16x16x32(kf0[1], qf[qt][1], s0);                                   \
      f32x4 s1 = MFMA_16x16x32(kf1[0], qf[qt][0], fzero);                          \
      s1 = MFMA_16x16x32(kf1[1], qf[qt][1], s1);                                   \
      u32x4 pw;                                                                    \
      pw[0] = pack2(exp2_fast(s0[0]), exp2_fast(s0[1]));                           \
      pw[1] = pack2(exp2_fast(s0[2]), exp2_fast(s0[3]));                           \
      pw[2] = pack2(exp2_fast(s1[0]), exp2_fast(s1[1]));                           \
      pw[3] = pack2(exp2_fast(s1[2]), exp2_fast(s1[3]));                           \
      short8 pf = __builtin_bit_cast(short8, pw);                                  \
      lacc[qt] = MFMA_16x16x32(ones, pf, lacc[qt]);                                \
      _Pragma("unroll")                                                            \
      for (int dt = 0; dt < 4; ++dt)                                               \
        acc[qt][dt] = MFMA_16x16x32(vf[dt], pf, acc[qt][dt]);                      \
    }                                                                              \
    __builtin_amdgcn_s_setprio(0);                                                 \
  }

  short8 qf[2][2];
#pragma unroll
  for (int qt = 0; qt < 2; ++qt)
#pragma unroll
    for (int hf = 0; hf < 2; ++hf)
      qf[qt][hf] = *(const short8*)&Q[base + (size_t)(q0 + qt * 16 + lq) * 64 + hf * 32 + G * 8];

  f32x4 acc[2][4];
#pragma unroll
  for (int qt = 0; qt < 2; ++qt)
#pragma unroll
    for (int dt = 0; dt < 4; ++dt) acc[qt][dt] = fzero;
  f32x4 lacc[2] = {fzero, fzero};              // row-sum accumulators (MFMA)

  STAGE_TILE(0, 0);
  __syncthreads();

  for (int it2 = 0; it2 < 16; ++it2) {
    const int kvc = it2 * 128;
    STAGE_TILE(kvc + 64, 1);
    TILE_COMPUTE(0)
    __syncthreads();                           // buf1 staged; buf0 reads done
    if (it2 != 15) {
      STAGE_TILE(kvc + 128, 0);
    }
    TILE_COMPUTE(1)
    __syncthreads();                           // buf0 staged; buf1 reads done
  }

  // O^T[d][q] -> out[b][s][h*64+d] (fp32); lane q = lq, d = dt*16 + 4G + r
#pragma unroll
  for (int qt = 0; qt < 2; ++qt) {
    float inv = 1.f / lacc[qt][0];             // full row sum (MFMA-reduced, all lanes)
    size_t rowoff = ((size_t)b * 2048 + q0 + qt * 16 + lq) * 1024 + h * 64;
#pragma unroll
    for (int dt = 0; dt < 4; ++dt) {
      f32x4 o;
#pragma unroll
      for (int r = 0; r < 4; ++r) o[r] = acc[qt][dt][r] * inv;
      *(f32x4*)&O[rowoff + dt * 16 + G * 4] = o;
    }
  }
#undef STAGE_TILE
#undef TILE_COMPUTE
}

extern "C" void kernel_launch(void* const* d_in, const int* in_sizes, int n_in,
                              void* d_out, int out_size, void* d_ws, size_t ws_size,
                              hipStream_t stream) {
  const float* x = (const float*)d_in[0];
  const float* wq = (const float*)d_in[1];
  const float* wk = (const float*)d_in[2];
  const float* wv = (const float*)d_in[3];
  float* out = (float*)d_out;            // fp32 output
  char* ws = (char*)d_ws;

  const size_t MB = 1024 * 1024;
  bf16* xbf = (bf16*)d_out;              // 16 MB scratch; dead before attn writes O
  bf16* wT = (bf16*)(ws);                // 6 MB
  bf16* qb = (bf16*)(ws + 6 * MB);       // 16 MB
  bf16* kb = (bf16*)(ws + 22 * MB);      // 16 MB
  bf16* vtb = (bf16*)(ws + 38 * MB);     // 16 MB

  hipLaunchKernelGGL(cvt_all_kernel, dim3(4864), dim3(256), 0, stream,
                     x, wq, wk, wv, xbf, wT);
  hipLaunchKernelGGL(qkv_gemm_kernel, dim3(1536), dim3(256), 0, stream, xbf, wT, qb, kb, vtb);
  hipLaunchKernelGGL(attn_kernel, dim3(1024), dim3(256), 0, stream, qb, kb, vtb, out);
}

// Round 23
// 156.409 us; speedup vs baseline: 1.0266x; 1.0237x over previous
//
#include <hip/hip_runtime.h>
#include <hip/hip_bf16.h>
#include <stdint.h>

// Problem: B=4, S=2048, D=1024, H=16, hd=64.
// fp32 inputs (x, wq, wk, wv), fp32 OUTPUT [B,S,D].
// Pipeline: cvt_all -> qkv_gemm (bf16 MFMA) -> flash attn.
// R21->R22: REVERT GEMM to R20's BK=32 kernel (R21's BK=64 regressed +3.4us:
// LDS 2x halved blocks/CU + 2x ds_read per fragment pass > barrier saving).
// This is the session-best configuration (156.7us): R17 GEMM (T2 swizzle,
// XCD swizzle, 8B vtb stores) + R20 attn (84.9us: K bit-perm, exp2 softmax,
// ones-MFMA row sums, setprio, precomputed base-pointer ds_reads).
// Buffer plan:
//   d_out[0,16M)  xbf  bf16 [8192][1024]  (scratch; dead before attn O-writes)
//   ws[0,6M)      wT   bf16 [3072][1024]
//   ws[6M,22M)    qb   bf16 [64 pair][2048][64]  (pre-scaled by 0.125*log2e)
//   ws[22M,38M)   kb   bf16 [64 pair][2048][64]
//   ws[38M,54M)   vtb  bf16 [64 pair][64][2048]  (V transposed)

typedef __hip_bfloat16 bf16;
typedef __attribute__((ext_vector_type(8))) short short8;
typedef __attribute__((ext_vector_type(4))) float f32x4;
typedef __attribute__((ext_vector_type(4))) unsigned int u32x4;
typedef __attribute__((ext_vector_type(8))) unsigned short ushort8;
typedef __attribute__((ext_vector_type(4))) unsigned short ushort4v;

#define MFMA_16x16x32(a, b, c) __builtin_amdgcn_mfma_f32_16x16x32_bf16((a), (b), (c), 0, 0, 0)

__device__ __forceinline__ void gload_lds16(const void* g, void* l) {
  __builtin_amdgcn_global_load_lds((const __attribute__((address_space(1))) unsigned int*)g,
                                   (__attribute__((address_space(3))) unsigned int*)l,
                                   16, 0, 0);
}

__device__ __forceinline__ unsigned short bfu(float f) {
  return __bfloat16_as_ushort(__float2bfloat16(f));
}
__device__ __forceinline__ unsigned int pack2(float lo, float hi) {
  unsigned int r;
  asm("v_cvt_pk_bf16_f32 %0, %1, %2" : "=v"(r) : "v"(lo), "v"(hi));
  return r;
}
__device__ __forceinline__ float exp2_fast(float x) {   // D = 2^S0 (ISA v_exp_f32)
  float r;
  asm("v_exp_f32 %0, %1" : "=v"(r) : "v"(x));
  return r;
}

// ---------- fused convert: x fp32->bf16  |  w fp32->bf16 transposed ----------
__global__ __launch_bounds__(256) void cvt_all_kernel(const float* __restrict__ x,
                                                      const float* __restrict__ w0,
                                                      const float* __restrict__ w1,
                                                      const float* __restrict__ w2,
                                                      bf16* __restrict__ xbf,
                                                      bf16* __restrict__ wT) {
  __shared__ float tile[64][65];
  const int t = threadIdx.x;
  const int bid = blockIdx.x;
  if (bid < 4096) {                      // ---- x convert: 8 elems/thread
    int i = bid * 256 + t;
    const float4* xv = (const float4*)x;
    float4 a = xv[i * 2];
    float4 b = xv[i * 2 + 1];
    ushort8 o;
    o[0] = bfu(a.x); o[1] = bfu(a.y); o[2] = bfu(a.z); o[3] = bfu(a.w);
    o[4] = bfu(b.x); o[5] = bfu(b.y); o[6] = bfu(b.z); o[7] = bfu(b.w);
    ((ushort8*)xbf)[i] = o;
    return;
  }
  // ---- w transpose+convert: w[k][n] -> wT[n][k]
  const int wb = bid - 4096;
  const int mat = wb >> 8;
  const int rem = wb & 255;
  const int k0 = (rem >> 4) * 64;
  const int n0 = (rem & 15) * 64;
  const float* w = (mat == 0) ? w0 : ((mat == 1) ? w1 : w2);
#pragma unroll
  for (int it = 0; it < 4; ++it) {
    int lin = it * 1024 + t * 4;
    int row = lin >> 6, col = lin & 63;
    float4 v = *(const float4*)&w[(size_t)(k0 + row) * 1024 + n0 + col];
    tile[row][col] = v.x; tile[row][col + 1] = v.y;
    tile[row][col + 2] = v.z; tile[row][col + 3] = v.w;
  }
  __syncthreads();
#pragma unroll
  for (int it = 0; it < 2; ++it) {
    int chunk = it * 256 + t;
    int nrow = chunk >> 3, kc = chunk & 7;
    ushort8 o;
#pragma unroll
    for (int j = 0; j < 8; ++j) o[j] = bfu(tile[kc * 8 + j][nrow]);
    *(ushort8*)&wT[((size_t)mat * 1024 + n0 + nrow) * 1024 + k0 + kc * 8] = o;
  }
}

// ---------------- QKV GEMM: [8192,1024] x [1024,3072] -------------------
// 128x128 tile, BK=32, 4 waves (2x2), 4x4 16x16x32 MFMA per wave.
// T2 XOR swizzle (2-way conflicts), T1 XCD grid swizzle, vtb 8B stores.
__global__ __launch_bounds__(256) void qkv_gemm_kernel(const bf16* __restrict__ A,
                                                       const bf16* __restrict__ Wt,
                                                       bf16* __restrict__ qb,
                                                       bf16* __restrict__ kb,
                                                       bf16* __restrict__ vtb) {
  __shared__ bf16 As[128 * 32];
  __shared__ bf16 Bs[128 * 32];
  const int t = threadIdx.x;
  const int w = t >> 6;
  const int lane = t & 63;
  const int G = lane >> 4, lq = lane & 15;
  const int bid = blockIdx.x;                  // 1536 blocks
  const int xcd = bid & 7, p = bid >> 3;       // p in [0,192)
  const int m0 = (xcd * 8 + (p & 7)) * 128;
  const int n0 = (p >> 3) * 128;
  const int wr = w >> 1, wc = w & 1;

  const f32x4 fzero = {0.f, 0.f, 0.f, 0.f};
  f32x4 acc[4][4];
#pragma unroll
  for (int i = 0; i < 4; ++i)
#pragma unroll
    for (int j = 0; j < 4; ++j) acc[i][j] = fzero;

  const int crow = t >> 2;                     // row within rep-half (0..63)
  const int ckc = t & 3;
  const int scs = (ckc ^ ((crow >> 1) & 3)) * 8;  // swizzled src elem offset
  const int fx = (lq >> 1) & 3;                // frag-read XOR term

  for (int k0 = 0; k0 < 1024; k0 += 32) {
#pragma unroll
    for (int rep = 0; rep < 2; ++rep) {
      int row = rep * 64 + crow;
      gload_lds16(&A[(size_t)(m0 + row) * 1024 + k0 + scs],
                  &As[(size_t)(rep * 256 + w * 64) * 8]);
      gload_lds16(&Wt[(size_t)(n0 + row) * 1024 + k0 + scs],
                  &Bs[(size_t)(rep * 256 + w * 64) * 8]);
    }
    __syncthreads();
    short8 af[4], bfr[4];
#pragma unroll
    for (int i = 0; i < 4; ++i)
      af[i] = *(const short8*)&As[(wr * 64 + i * 16 + lq) * 32 + (G ^ fx) * 8];
#pragma unroll
    for (int j = 0; j < 4; ++j)
      bfr[j] = *(const short8*)&Bs[(wc * 64 + j * 16 + lq) * 32 + (G ^ fx) * 8];
#pragma unroll
    for (int i = 0; i < 4; ++i)
#pragma unroll
      for (int j = 0; j < 4; ++j)
        acc[i][j] = MFMA_16x16x32(af[i], bfr[j], acc[i][j]);
    __syncthreads();
  }

  const int matid = n0 >> 10;
  const int nb = n0 & 1023;
  if (matid == 2) {
    // V^T: thread's 4 r-values are 4 consecutive s at fixed d -> 8B store
#pragma unroll
    for (int i = 0; i < 4; ++i) {
      int mm = m0 + wr * 64 + i * 16 + G * 4;  // r=0 base; 4 consecutive
      int b = mm >> 11, s = mm & 2047;
#pragma unroll
      for (int j = 0; j < 4; ++j) {
        int nn = nb + wc * 64 + j * 16 + lq;
        int h = nn >> 6, d = nn & 63;
        ushort4v o;
#pragma unroll
        for (int r = 0; r < 4; ++r) o[r] = bfu(acc[i][j][r]);
        *(ushort4v*)&vtb[((size_t)(b * 16 + h) * 64 + d) * 2048 + s] = o;
      }
    }
  } else {
    const float scale = (matid == 0) ? 0.18033688011112f : 1.0f;  // 1/8*log2e | 1
    bf16* dst = (matid == 0) ? qb : kb;
#pragma unroll
    for (int i = 0; i < 4; ++i) {
#pragma unroll
      for (int r = 0; r < 4; ++r) {
        int mm = m0 + wr * 64 + i * 16 + G * 4 + r;
        int b = mm >> 11, s = mm & 2047;
#pragma unroll
        for (int j = 0; j < 4; ++j) {
          int nn = nb + wc * 64 + j * 16 + lq;
          int h = nn >> 6, d = nn & 63;
          dst[((size_t)(b * 16 + h) * 2048 + s) * 64 + d] =
              __float2bfloat16(acc[i][j][r] * scale);
        }
      }
    }
  }
}

// ---------------- flash attention (MFMA, LDS-staged K/V, swapped QK^T) -----
// R20 kernel (proven 84.9us): KVBLK=64 double-buffered staging, K bit-perm
// (QK^T C-layout == PV B-frag lane-locally), XOR swizzle, exp2 softmax,
// ones-MFMA row sums, T5 setprio, precomputed base-pointer ds_reads.
__global__ __launch_bounds__(256) void attn_kernel(const bf16* __restrict__ Q,
                                                   const bf16* __restrict__ K,
                                                   const bf16* __restrict__ VT,
                                                   float* __restrict__ O) {
  __shared__ bf16 Kb[2][4096];                 // [buf][64 kv(perm)][64 d] swizzled
  __shared__ bf16 Vb[2][4096];                 // [buf][64 d][64 kv] swizzled
  const int t = threadIdx.x;
  const int w = t >> 6, lane = t & 63;
  const int G = lane >> 4, lq = lane & 15;
  const int sw = lq & 7;                       // frag-read swizzle
  const int bid = blockIdx.x;
  const int pair = (((bid >> 7) & 7) << 3) | (bid & 7);  // 16 chunks of a pair on one XCD
  const int chunk = (bid >> 3) & 15;
  const int b = pair >> 4, h = pair & 15;
  const size_t base = (size_t)pair * (2048 * 64);
  const int q0 = chunk * 128 + w * 32;         // 32 q-rows per wave

  const f32x4 fzero = {0.f, 0.f, 0.f, 0.f};
  short8 ones;                                 // bf16 1.0 x8 (A-frag for row sums)
#pragma unroll
  for (int j = 0; j < 8; ++j) ones[j] = (short)0x3F80;

  const int srow = t >> 3, sbc = t & 7;
  const int ssc = (sbc ^ (srow & 7)) * 8;      // swizzled chunk (involution, per dest row)
  const int kprow = ((srow & 12) << 1) | ((srow & 16) >> 2) | (srow & 3);  // perm32(srow)

  // lane-constant XOR variants shared by K(hf) and V(h2):
  const int e0 = (G ^ sw) * 8;                 // hf=0 / h2=0
  const int e1 = ((4 + G) ^ sw) * 8;           // hf=1 / h2=1
  // 8 precomputed LDS base pointers; all reads = base + compile-time offset
  const bf16* kB0[2] = { &Kb[0][lq * 64 + e0], &Kb[1][lq * 64 + e0] };
  const bf16* kB1[2] = { &Kb[0][lq * 64 + e1], &Kb[1][lq * 64 + e1] };
  const bf16* vB0[2] = { &Vb[0][lq * 64 + e0], &Vb[1][lq * 64 + e0] };
  const bf16* vB1[2] = { &Vb[0][lq * 64 + e1], &Vb[1][lq * 64 + e1] };

#define STAGE_TILE(kvbase, bufi)                                                   \
  do {                                                                             \
    gload_lds16(&K[base + (size_t)((kvbase) + kprow) * 64 + ssc],                  \
                &Kb[bufi][(size_t)(w * 64) * 8]);                                  \
    gload_lds16(&K[base + (size_t)((kvbase) + 32 + kprow) * 64 + ssc],             \
                &Kb[bufi][(size_t)(256 + w * 64) * 8]);                            \
    gload_lds16(&VT[base + (size_t)srow * 2048 + (kvbase) + ssc],                  \
                &Vb[bufi][(size_t)(w * 64) * 8]);                                  \
    gload_lds16(&VT[base + (size_t)(32 + srow) * 2048 + (kvbase) + ssc],           \
                &Vb[bufi][(size_t)(256 + w * 64) * 8]);                            \
  } while (0)

#define TILE_COMPUTE(BUF)                                                          \
  _Pragma("unroll")                                                                \
  for (int h2 = 0; h2 < 2; ++h2) {                                                 \
    short8 kf0[2], kf1[2], vf[4];                                                  \
    kf0[0] = *(const short8*)(kB0[BUF] + (h2 * 2 + 0) * 1024);                     \
    kf0[1] = *(const short8*)(kB1[BUF] + (h2 * 2 + 0) * 1024);                     \
    kf1[0] = *(const short8*)(kB0[BUF] + (h2 * 2 + 1) * 1024);                     \
    kf1[1] = *(const short8*)(kB1[BUF] + (h2 * 2 + 1) * 1024);                     \
    _Pragma("unroll")                                                              \
    for (int dt = 0; dt < 4; ++dt)                                                 \
      vf[dt] = h2 ? *(const short8*)(vB1[BUF] + dt * 1024)                         \
                  : *(const short8*)(vB0[BUF] + dt * 1024);                        \
    __builtin_amdgcn_s_setprio(1);                                                 \
    _Pragma("unroll")                                                              \
    for (int qt = 0; qt < 2; ++qt) {                                               \
      f32x4 s0 = MFMA_16x16x32(kf0[0], qf[qt][0], fzero);                          \
      s0 = MFMA_16x16x32(kf0[1], qf[qt][1], s0);                                   \
      f32x4 s1 = MFMA_16x16x32(kf1[0], qf[qt][0], fzero);                          \
      s1 = MFMA_16x16x32(kf1[1], qf[qt][1], s1);                                   \
      u32x4 pw;                                                                    \
      pw[0] = pack2(exp2_fast(s0[0]), exp2_fast(s0[1]));                           \
      pw[1] = pack2(exp2_fast(s0[2]), exp2_fast(s0[3]));                           \
      pw[2] = pack2(exp2_fast(s1[0]), exp2_fast(s1[1]));                           \
      pw[3] = pack2(exp2_fast(s1[2]), exp2_fast(s1[3]));                           \
      short8 pf = __builtin_bit_cast(short8, pw);                                  \
      lacc[qt] = MFMA_16x16x32(ones, pf, lacc[qt]);                                \
      _Pragma("unroll")                                                            \
      for (int dt = 0; dt < 4; ++dt)                                               \
        acc[qt][dt] = MFMA_16x16x32(vf[dt], pf, acc[qt][dt]);                      \
    }                                                                              \
    __builtin_amdgcn_s_setprio(0);                                                 \
  }

  short8 qf[2][2];
#pragma unroll
  for (int qt = 0; qt < 2; ++qt)
#pragma unroll
    for (int hf = 0; hf < 2; ++hf)
      qf[qt][hf] = *(const short8*)&Q[base + (size_t)(q0 + qt * 16 + lq) * 64 + hf * 32 + G * 8];

  f32x4 acc[2][4];
#pragma unroll
  for (int qt = 0; qt < 2; ++qt)
#pragma unroll
    for (int dt = 0; dt < 4; ++dt) acc[qt][dt] = fzero;
  f32x4 lacc[2] = {fzero, fzero};              // row-sum accumulators (MFMA)

  STAGE_TILE(0, 0);
  __syncthreads();

  for (int it2 = 0; it2 < 16; ++it2) {
    const int kvc = it2 * 128;
    STAGE_TILE(kvc + 64, 1);
    TILE_COMPUTE(0)
    __syncthreads();                           // buf1 staged; buf0 reads done
    if (it2 != 15) {
      STAGE_TILE(kvc + 128, 0);
    }
    TILE_COMPUTE(1)
    __syncthreads();                           // buf0 staged; buf1 reads done
  }

  // O^T[d][q] -> out[b][s][h*64+d] (fp32); lane q = lq, d = dt*16 + 4G + r
#pragma unroll
  for (int qt = 0; qt < 2; ++qt) {
    float inv = 1.f / lacc[qt][0];             // full row sum (MFMA-reduced, all lanes)
    size_t rowoff = ((size_t)b * 2048 + q0 + qt * 16 + lq) * 1024 + h * 64;
#pragma unroll
    for (int dt = 0; dt < 4; ++dt) {
      f32x4 o;
#pragma unroll
      for (int r = 0; r < 4; ++r) o[r] = acc[qt][dt][r] * inv;
      *(f32x4*)&O[rowoff + dt * 16 + G * 4] = o;
    }
  }
#undef STAGE_TILE
#undef TILE_COMPUTE
}

extern "C" void kernel_launch(void* const* d_in, const int* in_sizes, int n_in,
                              void* d_out, int out_size, void* d_ws, size_t ws_size,
                              hipStream_t stream) {
  const float* x = (const float*)d_in[0];
  const float* wq = (const float*)d_in[1];
  const float* wk = (const float*)d_in[2];
  const float* wv = (const float*)d_in[3];
  float* out = (float*)d_out;            // fp32 output
  char* ws = (char*)d_ws;

  const size_t MB = 1024 * 1024;
  bf16* xbf = (bf16*)d_out;              // 16 MB scratch; dead before attn writes O
  bf16* wT = (bf16*)(ws);                // 6 MB
  bf16* qb = (bf16*)(ws + 6 * MB);       // 16 MB
  bf16* kb = (bf16*)(ws + 22 * MB);      // 16 MB
  bf16* vtb = (bf16*)(ws + 38 * MB);     // 16 MB

  hipLaunchKernelGGL(cvt_all_kernel, dim3(4864), dim3(256), 0, stream,
                     x, wq, wk, wv, xbf, wT);
  hipLaunchKernelGGL(qkv_gemm_kernel, dim3(1536), dim3(256), 0, stream, xbf, wT, qb, kb, vtb);
  hipLaunchKernelGGL(attn_kernel, dim3(1024), dim3(256), 0, stream, qb, kb, vtb, out);
}